// Round 15
// baseline (562.537 us; speedup 1.0000x reference)
//
#include <hip/hip_runtime.h>

constexpr int N_NODES = 50000;
constexpr int N_EDGES = 800000;
constexpr int D = 64;

constexpr int NREG = 256;    // destination regions (one gin block each)
constexpr int RSZ = 196;     // nodes per region (256*196 = 50176 >= 50000)
constexpr int EPB = 4096;    // edges per prep block
constexpr int NBINB = 196;   // ceil(800000/4096)
constexpr int CELLCAP = 64;  // per-(region,block) cell cap; mean 16, P(>64) ~ 1e-20
constexpr int RECAP = 4608;  // per-region edge cap; mean 3136, sigma 56

// Workspace layout:
//   cnt2 [NREG*NBINB] ints          at int 0     (200 KB)
//   rbuf [NREG*NBINB*CELLCAP] ints  at int 50176 (12.8 MB, 256B cells)
constexpr int WS_CNT2 = 0;
constexpr int WS_RBUF = 50176;

// Edge binning only (bf16 conversion dropped — gather is latency-bound, not
// byte-bound: R4 vs R6 and R8 vs R13 both ~neutral). LDS int cursors.
__global__ __launch_bounds__(1024) void prep_kernel(
    const int* __restrict__ src, const int* __restrict__ dst,
    int* __restrict__ cnt2, unsigned* __restrict__ rbuf) {
  __shared__ int cur[NREG];
  int tid = threadIdx.x, blk = blockIdx.x;
  if (tid < NREG) cur[tid] = 0;

  int e0 = blk * EPB + tid * 4;
  bool valid = (e0 + 4 <= N_EDGES);  // N_EDGES % 4 == 0
  int4 d4 = {0, 0, 0, 0}, s4 = {0, 0, 0, 0};
  if (valid) {
    d4 = *reinterpret_cast<const int4*>(dst + e0);
    s4 = *reinterpret_cast<const int4*>(src + e0);
  }
  __syncthreads();

  if (valid) {
    const int dd[4] = {d4.x, d4.y, d4.z, d4.w};
    const int ss[4] = {s4.x, s4.y, s4.z, s4.w};
#pragma unroll
    for (int k = 0; k < 4; ++k) {
      int r = dd[k] / RSZ;  // magic-mul
      unsigned pk = ((unsigned)(dd[k] - r * RSZ) << 16) | (unsigned)ss[k];
      int p = atomicAdd(&cur[r], 1);
      if (p < CELLCAP)
        rbuf[(size_t)(r * NBINB + blk) * CELLCAP + p] = pk;
    }
  }
  __syncthreads();
  if (tid < NREG) {
    int c = cur[tid];
    cnt2[tid * NBINB + blk] = (c > CELLCAP) ? CELLCAP : c;
  }
}

// One block per region. Prologue = R14's proven wave-scan sort. Gather is
// fp32, 8-lane groups, TWO nodes per group (separate named arrays — no
// runtime pointer selects, R12 spill bug). The matvec is fused over the node
// pair so each Wt LDS read feeds 2 FMAs (halves the LDS-bound matvec cost).
__global__ __launch_bounds__(1024) void gin_kernel(
    const float* __restrict__ feat, const float* __restrict__ W,
    const float* __restrict__ b, const float* __restrict__ eps,
    const int* __restrict__ cnt2, const unsigned* __restrict__ rbuf,
    float* __restrict__ out) {
  __shared__ float Wt[D * D];       // 16 KB: Wt[i*64+o] = W[o*64+i]
  __shared__ unsigned ebuf[RECAP];  // 18 KB
  __shared__ ushort sorted[RECAP];  // 9 KB
  __shared__ int cellstart[NBINB + 1];
  __shared__ int hist[RSZ], nstart[RSZ + 1], cursor[RSZ];
  __shared__ int wsum[4], wsum2[4];

  int tid = threadIdx.x, r = blockIdx.x;
  int lane = tid & 63, wv = tid >> 6;
  for (int q = tid; q < D * D; q += 1024) Wt[q] = W[((q & 63) << 6) + (q >> 6)];
  if (tid < RSZ) hist[tid] = 0;

  // ---- scan 1: 196 cell counts, wave-level ----
  int c = (tid < NBINB) ? cnt2[r * NBINB + tid] : 0;
  int inc = c;
#pragma unroll
  for (int dlt = 1; dlt < 64; dlt <<= 1) {
    int t = __shfl_up(inc, (unsigned)dlt, 64);
    if (lane >= dlt) inc += t;
  }
  if (tid < 256 && lane == 63) wsum[wv] = inc;
  __syncthreads();  // B1
  if (tid < 256) {
    int prefix = inc - c;
    if (wv > 0) prefix += wsum[0];
    if (wv > 1) prefix += wsum[1];
    if (wv > 2) prefix += wsum[2];
    if (tid < NBINB) cellstart[tid] = prefix;
  }
  if (tid == 0) cellstart[NBINB] = wsum[0] + wsum[1] + wsum[2] + wsum[3];
  __syncthreads();  // B2
  int T = cellstart[NBINB];
  if (T > RECAP) T = RECAP;

  {  // Concatenate cells into ebuf: 4 threads per cell, uint4 loads.
    int cell = tid >> 2, sub = tid & 3;
    if (cell < NBINB) {
      int cs = cellstart[cell];
      int cc = cellstart[cell + 1] - cs;
      const unsigned* cp = rbuf + (size_t)(r * NBINB + cell) * CELLCAP;
      for (int i = sub * 4; i < cc; i += 16) {
        uint4 v = *reinterpret_cast<const uint4*>(cp + i);
        if (cs + i + 0 < T && i + 0 < cc) ebuf[cs + i + 0] = v.x;
        if (cs + i + 1 < T && i + 1 < cc) ebuf[cs + i + 1] = v.y;
        if (cs + i + 2 < T && i + 2 < cc) ebuf[cs + i + 2] = v.z;
        if (cs + i + 3 < T && i + 3 < cc) ebuf[cs + i + 3] = v.w;
      }
    }
  }
  __syncthreads();  // B3

  for (int e = tid; e < T; e += 1024) atomicAdd(&hist[ebuf[e] >> 16], 1);
  __syncthreads();  // B4

  // ---- scan 2: 196 node counts, wave-level ----
  int h = (tid < RSZ) ? hist[tid] : 0;
  int inc2 = h;
#pragma unroll
  for (int dlt = 1; dlt < 64; dlt <<= 1) {
    int t = __shfl_up(inc2, (unsigned)dlt, 64);
    if (lane >= dlt) inc2 += t;
  }
  if (tid < 256 && lane == 63) wsum2[wv] = inc2;
  __syncthreads();  // B5
  if (tid < 256) {
    int prefix = inc2 - h;
    if (wv > 0) prefix += wsum2[0];
    if (wv > 1) prefix += wsum2[1];
    if (wv > 2) prefix += wsum2[2];
    if (tid < RSZ) {
      nstart[tid] = prefix;
      cursor[tid] = prefix;
    }
  }
  if (tid == 0) nstart[RSZ] = wsum2[0] + wsum2[1] + wsum2[2] + wsum2[3];
  __syncthreads();  // B6
  for (int e = tid; e < T; e += 1024) {
    unsigned pk = ebuf[e];
    int p = atomicAdd(&cursor[pk >> 16], 1);
    sorted[p] = (ushort)(pk & 0xFFFFu);
  }
  __syncthreads();  // B7

  // 128 groups x 8 lanes; lane owns feature slots j8..j8+7 (32 B fp32).
  int g = tid >> 3, j8 = (tid & 7) << 3;
  float s = 1.0f + eps[0];

  int nA = g, nB = g + 128;
  int nodeA = r * RSZ + nA, nodeB = r * RSZ + nB;
  bool vA = (nodeA < N_NODES);                 // nA < RSZ always
  bool vB = (nB < RSZ) && (nodeB < N_NODES);

  float aA[8] = {0, 0, 0, 0, 0, 0, 0, 0};
  float aB[8] = {0, 0, 0, 0, 0, 0, 0, 0};

  // ---- gather node A ----
  if (vA) {
    const float4 fa = *reinterpret_cast<const float4*>(feat + (nodeA << 6) + j8);
    const float4 fb = *reinterpret_cast<const float4*>(feat + (nodeA << 6) + j8 + 4);
    aA[0] = s * fa.x; aA[1] = s * fa.y; aA[2] = s * fa.z; aA[3] = s * fa.w;
    aA[4] = s * fb.x; aA[5] = s * fb.y; aA[6] = s * fb.z; aA[7] = s * fb.w;
    int e = nstart[nA], e1 = nstart[nA + 1];
    for (; e + 4 <= e1; e += 4) {
      int s0 = sorted[e], s1 = sorted[e + 1], s2 = sorted[e + 2], s3 = sorted[e + 3];
      const float4 p0 = *reinterpret_cast<const float4*>(feat + (s0 << 6) + j8);
      const float4 q0 = *reinterpret_cast<const float4*>(feat + (s0 << 6) + j8 + 4);
      const float4 p1 = *reinterpret_cast<const float4*>(feat + (s1 << 6) + j8);
      const float4 q1 = *reinterpret_cast<const float4*>(feat + (s1 << 6) + j8 + 4);
      const float4 p2 = *reinterpret_cast<const float4*>(feat + (s2 << 6) + j8);
      const float4 q2 = *reinterpret_cast<const float4*>(feat + (s2 << 6) + j8 + 4);
      const float4 p3 = *reinterpret_cast<const float4*>(feat + (s3 << 6) + j8);
      const float4 q3 = *reinterpret_cast<const float4*>(feat + (s3 << 6) + j8 + 4);
      aA[0] += (p0.x + p1.x) + (p2.x + p3.x);
      aA[1] += (p0.y + p1.y) + (p2.y + p3.y);
      aA[2] += (p0.z + p1.z) + (p2.z + p3.z);
      aA[3] += (p0.w + p1.w) + (p2.w + p3.w);
      aA[4] += (q0.x + q1.x) + (q2.x + q3.x);
      aA[5] += (q0.y + q1.y) + (q2.y + q3.y);
      aA[6] += (q0.z + q1.z) + (q2.z + q3.z);
      aA[7] += (q0.w + q1.w) + (q2.w + q3.w);
    }
    for (; e < e1; ++e) {
      int sn = sorted[e];
      const float4 p = *reinterpret_cast<const float4*>(feat + (sn << 6) + j8);
      const float4 q = *reinterpret_cast<const float4*>(feat + (sn << 6) + j8 + 4);
      aA[0] += p.x; aA[1] += p.y; aA[2] += p.z; aA[3] += p.w;
      aA[4] += q.x; aA[5] += q.y; aA[6] += q.z; aA[7] += q.w;
    }
  }

  // ---- gather node B (separate named code — no pointer select) ----
  if (vB) {
    const float4 fa = *reinterpret_cast<const float4*>(feat + (nodeB << 6) + j8);
    const float4 fb = *reinterpret_cast<const float4*>(feat + (nodeB << 6) + j8 + 4);
    aB[0] = s * fa.x; aB[1] = s * fa.y; aB[2] = s * fa.z; aB[3] = s * fa.w;
    aB[4] = s * fb.x; aB[5] = s * fb.y; aB[6] = s * fb.z; aB[7] = s * fb.w;
    int e = nstart[nB], e1 = nstart[nB + 1];
    for (; e + 4 <= e1; e += 4) {
      int s0 = sorted[e], s1 = sorted[e + 1], s2 = sorted[e + 2], s3 = sorted[e + 3];
      const float4 p0 = *reinterpret_cast<const float4*>(feat + (s0 << 6) + j8);
      const float4 q0 = *reinterpret_cast<const float4*>(feat + (s0 << 6) + j8 + 4);
      const float4 p1 = *reinterpret_cast<const float4*>(feat + (s1 << 6) + j8);
      const float4 q1 = *reinterpret_cast<const float4*>(feat + (s1 << 6) + j8 + 4);
      const float4 p2 = *reinterpret_cast<const float4*>(feat + (s2 << 6) + j8);
      const float4 q2 = *reinterpret_cast<const float4*>(feat + (s2 << 6) + j8 + 4);
      const float4 p3 = *reinterpret_cast<const float4*>(feat + (s3 << 6) + j8);
      const float4 q3 = *reinterpret_cast<const float4*>(feat + (s3 << 6) + j8 + 4);
      aB[0] += (p0.x + p1.x) + (p2.x + p3.x);
      aB[1] += (p0.y + p1.y) + (p2.y + p3.y);
      aB[2] += (p0.z + p1.z) + (p2.z + p3.z);
      aB[3] += (p0.w + p1.w) + (p2.w + p3.w);
      aB[4] += (q0.x + q1.x) + (q2.x + q3.x);
      aB[5] += (q0.y + q1.y) + (q2.y + q3.y);
      aB[6] += (q0.z + q1.z) + (q2.z + q3.z);
      aB[7] += (q0.w + q1.w) + (q2.w + q3.w);
    }
    for (; e < e1; ++e) {
      int sn = sorted[e];
      const float4 p = *reinterpret_cast<const float4*>(feat + (sn << 6) + j8);
      const float4 q = *reinterpret_cast<const float4*>(feat + (sn << 6) + j8 + 4);
      aB[0] += p.x; aB[1] += p.y; aB[2] += p.z; aB[3] += p.w;
      aB[4] += q.x; aB[5] += q.y; aB[6] += q.z; aB[7] += q.w;
    }
  }

  // ---- fused matvec: each Wt read feeds both nodes ----
  float rA[8], rB[8];
  {
    const float4 ba = *reinterpret_cast<const float4*>(b + j8);
    const float4 bb = *reinterpret_cast<const float4*>(b + j8 + 4);
    rA[0] = ba.x; rA[1] = ba.y; rA[2] = ba.z; rA[3] = ba.w;
    rA[4] = bb.x; rA[5] = bb.y; rA[6] = bb.z; rA[7] = bb.w;
#pragma unroll
    for (int k = 0; k < 8; ++k) rB[k] = rA[k];
  }
#pragma unroll
  for (int i = 0; i < D; ++i) {
    float va = __shfl(aA[i & 7], i >> 3, 8);
    float vb = __shfl(aB[i & 7], i >> 3, 8);
    const float4 wa = *reinterpret_cast<const float4*>(Wt + i * D + j8);
    const float4 wb = *reinterpret_cast<const float4*>(Wt + i * D + j8 + 4);
    rA[0] += va * wa.x; rA[1] += va * wa.y; rA[2] += va * wa.z; rA[3] += va * wa.w;
    rA[4] += va * wb.x; rA[5] += va * wb.y; rA[6] += va * wb.z; rA[7] += va * wb.w;
    rB[0] += vb * wa.x; rB[1] += vb * wa.y; rB[2] += vb * wa.z; rB[3] += vb * wa.w;
    rB[4] += vb * wb.x; rB[5] += vb * wb.y; rB[6] += vb * wb.z; rB[7] += vb * wb.w;
  }
  if (vA) {
    float4 o0, o1;
    o0.x = rA[0]; o0.y = rA[1]; o0.z = rA[2]; o0.w = rA[3];
    o1.x = rA[4]; o1.y = rA[5]; o1.z = rA[6]; o1.w = rA[7];
    *reinterpret_cast<float4*>(out + (nodeA << 6) + j8) = o0;
    *reinterpret_cast<float4*>(out + (nodeA << 6) + j8 + 4) = o1;
  }
  if (vB) {
    float4 o0, o1;
    o0.x = rB[0]; o0.y = rB[1]; o0.z = rB[2]; o0.w = rB[3];
    o1.x = rB[4]; o1.y = rB[5]; o1.z = rB[6]; o1.w = rB[7];
    *reinterpret_cast<float4*>(out + (nodeB << 6) + j8) = o0;
    *reinterpret_cast<float4*>(out + (nodeB << 6) + j8 + 4) = o1;
  }
}

extern "C" void kernel_launch(void* const* d_in, const int* in_sizes, int n_in,
                              void* d_out, int out_size, void* d_ws, size_t ws_size,
                              hipStream_t stream) {
  const float* feat = (const float*)d_in[0];
  const float* W    = (const float*)d_in[1];
  const float* b    = (const float*)d_in[2];
  const float* eps  = (const float*)d_in[3];
  const int*   src  = (const int*)d_in[4];
  const int*   dst  = (const int*)d_in[5];
  float* out = (float*)d_out;

  int* ws = (int*)d_ws;
  int* cnt2      = ws + WS_CNT2;
  unsigned* rbuf = (unsigned*)(ws + WS_RBUF);

  hipLaunchKernelGGL(prep_kernel, dim3(NBINB), dim3(1024), 0, stream,
                     src, dst, cnt2, rbuf);
  hipLaunchKernelGGL(gin_kernel, dim3(NREG), dim3(1024), 0, stream,
                     feat, W, b, eps, cnt2, rbuf, out);
}

// Round 16
// 109.899 us; speedup vs baseline: 5.1187x; 5.1187x over previous
//
#include <hip/hip_runtime.h>

constexpr int N_NODES = 50000;
constexpr int N_EDGES = 800000;
constexpr int D = 64;

constexpr int NREG = 256;    // destination regions (one gin block each)
constexpr int RSZ = 196;     // nodes per region (256*196 = 50176 >= 50000)
constexpr int EPB = 4096;    // edges per prep block
constexpr int NBINB = 196;   // ceil(800000/4096)
constexpr int CELLCAP = 64;  // per-(region,block) cell cap; mean 16, P(>64) ~ 1e-20
constexpr int RECAP = 4608;  // per-region edge cap; mean 3136, sigma 56

// Workspace layout:
//   cnt2 [NREG*NBINB] ints          at int 0          (200 KB)
//   rbuf [NREG*NBINB*CELLCAP] ints  at int 50176      (12.8 MB, 256B cells)
//   hb   [N_NODES*D] ushorts        at byte 13045760  (6.4 MB)
constexpr int WS_CNT2 = 0;
constexpr int WS_RBUF = 50176;
constexpr size_t WS_HB_BYTE = (size_t)(50176 + (size_t)NREG * NBINB * CELLCAP) * 4;

__device__ __forceinline__ ushort to_bf16(float x) {
  unsigned u = __float_as_uint(x);
  u += 0x7FFF + ((u >> 16) & 1);  // RNE
  return (ushort)(u >> 16);
}
__device__ __forceinline__ float bf_lo(unsigned u) {
  return __uint_as_float(u << 16);
}
__device__ __forceinline__ float bf_hi(unsigned u) {
  return __uint_as_float(u & 0xFFFF0000u);
}

// Fused: feat->bf16 conversion slice + edge binning into per-(region,block)
// cells via LDS int cursors. EXACT copy of the R8/R13/R14 kernel.
__global__ __launch_bounds__(1024) void prep_kernel(
    const float4* __restrict__ feat4, const int* __restrict__ src,
    const int* __restrict__ dst, ushort* __restrict__ hb,
    int* __restrict__ cnt2, unsigned* __restrict__ rbuf) {
  __shared__ int cur[NREG];
  int tid = threadIdx.x, blk = blockIdx.x;
  if (tid < NREG) cur[tid] = 0;

  int e0 = blk * EPB + tid * 4;
  bool valid = (e0 + 4 <= N_EDGES);  // N_EDGES % 4 == 0
  int4 d4 = {0, 0, 0, 0}, s4 = {0, 0, 0, 0};
  if (valid) {
    d4 = *reinterpret_cast<const int4*>(dst + e0);
    s4 = *reinterpret_cast<const int4*>(src + e0);
  }

  // bf16 conversion: 4096 float4 per block (196*4096 >= 800000 float4s).
  int cb = blk * 4096 + tid;
#pragma unroll
  for (int k = 0; k < 4; ++k) {
    int t = cb + k * 1024;
    if (t < N_NODES * D / 4) {
      float4 f = feat4[t];
      ushort4 h;
      h.x = to_bf16(f.x); h.y = to_bf16(f.y);
      h.z = to_bf16(f.z); h.w = to_bf16(f.w);
      *reinterpret_cast<ushort4*>(hb + t * 4) = h;
    }
  }
  __syncthreads();

  if (valid) {
    const int dd[4] = {d4.x, d4.y, d4.z, d4.w};
    const int ss[4] = {s4.x, s4.y, s4.z, s4.w};
#pragma unroll
    for (int k = 0; k < 4; ++k) {
      int r = dd[k] / RSZ;  // magic-mul
      unsigned pk = ((unsigned)(dd[k] - r * RSZ) << 16) | (unsigned)ss[k];
      int p = atomicAdd(&cur[r], 1);
      if (p < CELLCAP)
        rbuf[(size_t)(r * NBINB + blk) * CELLCAP + p] = pk;
    }
  }
  __syncthreads();
  if (tid < NREG) {
    int c = cur[tid];
    cnt2[tid * NBINB + blk] = (c > CELLCAP) ? CELLCAP : c;
  }
}

// One block per region. Wave-scan sort prologue; 8-lane-group bf16 gather
// (one uint4/lane/edge); ONE node per group at a time (two-node register
// blocking spills at the 128-VGPR cap of 1024-thread blocks — R12/R15).
__global__ __launch_bounds__(1024) void gin_kernel(
    const float* __restrict__ feat, const ushort* __restrict__ hb,
    const float* __restrict__ W, const float* __restrict__ b,
    const float* __restrict__ eps, const int* __restrict__ cnt2,
    const unsigned* __restrict__ rbuf, float* __restrict__ out) {
  __shared__ float Wt[D * D];       // 16 KB: Wt[i*64+o] = W[o*64+i]
  __shared__ unsigned ebuf[RECAP];  // 18 KB
  __shared__ ushort sorted[RECAP];  // 9 KB
  __shared__ int cellstart[NBINB + 1];
  __shared__ int hist[RSZ], nstart[RSZ + 1], cursor[RSZ];
  __shared__ int wsum[4], wsum2[4];

  int tid = threadIdx.x, r = blockIdx.x;
  int lane = tid & 63, wv = tid >> 6;
  for (int q = tid; q < D * D; q += 1024) Wt[q] = W[((q & 63) << 6) + (q >> 6)];
  if (tid < RSZ) hist[tid] = 0;

  // ---- scan 1: 196 cell counts, wave-level (no barriers inside) ----
  int c = (tid < NBINB) ? cnt2[r * NBINB + tid] : 0;
  int inc = c;
#pragma unroll
  for (int dlt = 1; dlt < 64; dlt <<= 1) {
    int t = __shfl_up(inc, (unsigned)dlt, 64);
    if (lane >= dlt) inc += t;
  }
  if (tid < 256 && lane == 63) wsum[wv] = inc;
  __syncthreads();  // B1
  if (tid < 256) {
    int prefix = inc - c;
    if (wv > 0) prefix += wsum[0];
    if (wv > 1) prefix += wsum[1];
    if (wv > 2) prefix += wsum[2];
    if (tid < NBINB) cellstart[tid] = prefix;
  }
  if (tid == 0) cellstart[NBINB] = wsum[0] + wsum[1] + wsum[2] + wsum[3];
  __syncthreads();  // B2
  int T = cellstart[NBINB];
  if (T > RECAP) T = RECAP;  // statistically impossible

  {  // Concatenate cells into ebuf: 4 threads per cell, uint4 loads.
    int cell = tid >> 2, sub = tid & 3;
    if (cell < NBINB) {
      int cs = cellstart[cell];
      int cc = cellstart[cell + 1] - cs;
      const unsigned* cp = rbuf + (size_t)(r * NBINB + cell) * CELLCAP;
      for (int i = sub * 4; i < cc; i += 16) {
        uint4 v = *reinterpret_cast<const uint4*>(cp + i);
        if (cs + i + 0 < T && i + 0 < cc) ebuf[cs + i + 0] = v.x;
        if (cs + i + 1 < T && i + 1 < cc) ebuf[cs + i + 1] = v.y;
        if (cs + i + 2 < T && i + 2 < cc) ebuf[cs + i + 2] = v.z;
        if (cs + i + 3 < T && i + 3 < cc) ebuf[cs + i + 3] = v.w;
      }
    }
  }
  __syncthreads();  // B3

  // Histogram by local node (int LDS atomics — cheap).
  for (int e = tid; e < T; e += 1024) atomicAdd(&hist[ebuf[e] >> 16], 1);
  __syncthreads();  // B4

  // ---- scan 2: 196 node counts, wave-level ----
  int h = (tid < RSZ) ? hist[tid] : 0;
  int inc2 = h;
#pragma unroll
  for (int dlt = 1; dlt < 64; dlt <<= 1) {
    int t = __shfl_up(inc2, (unsigned)dlt, 64);
    if (lane >= dlt) inc2 += t;
  }
  if (tid < 256 && lane == 63) wsum2[wv] = inc2;
  __syncthreads();  // B5
  if (tid < 256) {
    int prefix = inc2 - h;
    if (wv > 0) prefix += wsum2[0];
    if (wv > 1) prefix += wsum2[1];
    if (wv > 2) prefix += wsum2[2];
    if (tid < RSZ) {
      nstart[tid] = prefix;
      cursor[tid] = prefix;
    }
  }
  if (tid == 0) nstart[RSZ] = wsum2[0] + wsum2[1] + wsum2[2] + wsum2[3];
  __syncthreads();  // B6
  for (int e = tid; e < T; e += 1024) {
    unsigned pk = ebuf[e];
    int p = atomicAdd(&cursor[pk >> 16], 1);
    sorted[p] = (ushort)(pk & 0xFFFFu);
  }
  __syncthreads();  // B7

  // 128 groups x 8 lanes; lane owns feature slots j8..j8+7 (one uint4 of hb).
  int g = tid >> 3, j8 = (tid & 7) << 3;
  float s = 1.0f + eps[0];

  for (int n = g; n < RSZ; n += 128) {  // 2 iterations
    int node = r * RSZ + n;
    if (node >= N_NODES) continue;  // group-uniform

    float acc[8];
    {  // self term in fp32 (exact residual path)
      const float4 fa = *reinterpret_cast<const float4*>(feat + (node << 6) + j8);
      const float4 fb = *reinterpret_cast<const float4*>(feat + (node << 6) + j8 + 4);
      acc[0] = s * fa.x; acc[1] = s * fa.y; acc[2] = s * fa.z; acc[3] = s * fa.w;
      acc[4] = s * fb.x; acc[5] = s * fb.y; acc[6] = s * fb.z; acc[7] = s * fb.w;
    }

    int e = nstart[n], e1 = nstart[n + 1];
    for (; e + 8 <= e1; e += 8) {
      int i0 = sorted[e + 0], i1 = sorted[e + 1], i2 = sorted[e + 2], i3 = sorted[e + 3];
      int i4_ = sorted[e + 4], i5 = sorted[e + 5], i6 = sorted[e + 6], i7 = sorted[e + 7];
      const uint4 h0 = *reinterpret_cast<const uint4*>(hb + (i0 << 6) + j8);
      const uint4 h1 = *reinterpret_cast<const uint4*>(hb + (i1 << 6) + j8);
      const uint4 h2 = *reinterpret_cast<const uint4*>(hb + (i2 << 6) + j8);
      const uint4 h3 = *reinterpret_cast<const uint4*>(hb + (i3 << 6) + j8);
      const uint4 h4 = *reinterpret_cast<const uint4*>(hb + (i4_ << 6) + j8);
      const uint4 h5 = *reinterpret_cast<const uint4*>(hb + (i5 << 6) + j8);
      const uint4 h6 = *reinterpret_cast<const uint4*>(hb + (i6 << 6) + j8);
      const uint4 h7 = *reinterpret_cast<const uint4*>(hb + (i7 << 6) + j8);
      acc[0] += (bf_lo(h0.x) + bf_lo(h1.x)) + (bf_lo(h2.x) + bf_lo(h3.x))
              + (bf_lo(h4.x) + bf_lo(h5.x)) + (bf_lo(h6.x) + bf_lo(h7.x));
      acc[1] += (bf_hi(h0.x) + bf_hi(h1.x)) + (bf_hi(h2.x) + bf_hi(h3.x))
              + (bf_hi(h4.x) + bf_hi(h5.x)) + (bf_hi(h6.x) + bf_hi(h7.x));
      acc[2] += (bf_lo(h0.y) + bf_lo(h1.y)) + (bf_lo(h2.y) + bf_lo(h3.y))
              + (bf_lo(h4.y) + bf_lo(h5.y)) + (bf_lo(h6.y) + bf_lo(h7.y));
      acc[3] += (bf_hi(h0.y) + bf_hi(h1.y)) + (bf_hi(h2.y) + bf_hi(h3.y))
              + (bf_hi(h4.y) + bf_hi(h5.y)) + (bf_hi(h6.y) + bf_hi(h7.y));
      acc[4] += (bf_lo(h0.z) + bf_lo(h1.z)) + (bf_lo(h2.z) + bf_lo(h3.z))
              + (bf_lo(h4.z) + bf_lo(h5.z)) + (bf_lo(h6.z) + bf_lo(h7.z));
      acc[5] += (bf_hi(h0.z) + bf_hi(h1.z)) + (bf_hi(h2.z) + bf_hi(h3.z))
              + (bf_hi(h4.z) + bf_hi(h5.z)) + (bf_hi(h6.z) + bf_hi(h7.z));
      acc[6] += (bf_lo(h0.w) + bf_lo(h1.w)) + (bf_lo(h2.w) + bf_lo(h3.w))
              + (bf_lo(h4.w) + bf_lo(h5.w)) + (bf_lo(h6.w) + bf_lo(h7.w));
      acc[7] += (bf_hi(h0.w) + bf_hi(h1.w)) + (bf_hi(h2.w) + bf_hi(h3.w))
              + (bf_hi(h4.w) + bf_hi(h5.w)) + (bf_hi(h6.w) + bf_hi(h7.w));
    }
    for (; e < e1; ++e) {
      int sn = sorted[e];
      const uint4 hv = *reinterpret_cast<const uint4*>(hb + (sn << 6) + j8);
      acc[0] += bf_lo(hv.x); acc[1] += bf_hi(hv.x);
      acc[2] += bf_lo(hv.y); acc[3] += bf_hi(hv.y);
      acc[4] += bf_lo(hv.z); acc[5] += bf_hi(hv.z);
      acc[6] += bf_lo(hv.w); acc[7] += bf_hi(hv.w);
    }

    // Matvec: feature i lives in lane (i>>3), slot (i&7) — both constant
    // under full unroll, so acc stays in registers (SROA-safe).
    float res[8];
    {
      const float4 ba = *reinterpret_cast<const float4*>(b + j8);
      const float4 bb = *reinterpret_cast<const float4*>(b + j8 + 4);
      res[0] = ba.x; res[1] = ba.y; res[2] = ba.z; res[3] = ba.w;
      res[4] = bb.x; res[5] = bb.y; res[6] = bb.z; res[7] = bb.w;
    }
#pragma unroll
    for (int i = 0; i < D; ++i) {
      float rv = __shfl(acc[i & 7], i >> 3, 8);  // rst[node][i]
      const float4 wa = *reinterpret_cast<const float4*>(Wt + i * D + j8);
      const float4 wb = *reinterpret_cast<const float4*>(Wt + i * D + j8 + 4);
      res[0] += rv * wa.x; res[1] += rv * wa.y;
      res[2] += rv * wa.z; res[3] += rv * wa.w;
      res[4] += rv * wb.x; res[5] += rv * wb.y;
      res[6] += rv * wb.z; res[7] += rv * wb.w;
    }
    float4 o0, o1;
    o0.x = res[0]; o0.y = res[1]; o0.z = res[2]; o0.w = res[3];
    o1.x = res[4]; o1.y = res[5]; o1.z = res[6]; o1.w = res[7];
    *reinterpret_cast<float4*>(out + (node << 6) + j8) = o0;
    *reinterpret_cast<float4*>(out + (node << 6) + j8 + 4) = o1;
  }
}

extern "C" void kernel_launch(void* const* d_in, const int* in_sizes, int n_in,
                              void* d_out, int out_size, void* d_ws, size_t ws_size,
                              hipStream_t stream) {
  const float* feat = (const float*)d_in[0];
  const float* W    = (const float*)d_in[1];
  const float* b    = (const float*)d_in[2];
  const float* eps  = (const float*)d_in[3];
  const int*   src  = (const int*)d_in[4];
  const int*   dst  = (const int*)d_in[5];
  float* out = (float*)d_out;

  int* ws = (int*)d_ws;
  int* cnt2      = ws + WS_CNT2;
  unsigned* rbuf = (unsigned*)(ws + WS_RBUF);
  ushort* hb     = (ushort*)((char*)d_ws + WS_HB_BYTE);

  hipLaunchKernelGGL(prep_kernel, dim3(NBINB), dim3(1024), 0, stream,
                     (const float4*)feat, src, dst, hb, cnt2, rbuf);
  hipLaunchKernelGGL(gin_kernel, dim3(NREG), dim3(1024), 0, stream,
                     feat, hb, W, b, eps, cnt2, rbuf, out);
}

// Round 17
// 108.458 us; speedup vs baseline: 5.1867x; 1.0133x over previous
//
#include <hip/hip_runtime.h>

constexpr int N_NODES = 50000;
constexpr int N_EDGES = 800000;
constexpr int D = 64;

constexpr int NREG = 256;    // destination regions (one gin block each)
constexpr int RSZ = 196;     // nodes per region (256*196 = 50176 >= 50000)
constexpr int EPB = 4096;    // edges per prep block
constexpr int NBINB = 196;   // ceil(800000/4096)
constexpr int CELLCAP = 64;  // per-(region,block) cell cap; mean 16, P(>64) ~ 1e-20
constexpr int RECAP = 4608;  // per-region edge cap; mean 3136, sigma 56

// Workspace layout:
//   cnt2 [NREG*NBINB] ints          at int 0          (200 KB)
//   rbuf [NREG*NBINB*CELLCAP] ints  at int 50176      (12.8 MB, 256B cells)
//   hb   [N_NODES*D] ushorts        at byte 13045760  (6.4 MB)
constexpr int WS_CNT2 = 0;
constexpr int WS_RBUF = 50176;
constexpr size_t WS_HB_BYTE = (size_t)(50176 + (size_t)NREG * NBINB * CELLCAP) * 4;

__device__ __forceinline__ ushort to_bf16(float x) {
  unsigned u = __float_as_uint(x);
  u += 0x7FFF + ((u >> 16) & 1);  // RNE
  return (ushort)(u >> 16);
}
__device__ __forceinline__ float bf_lo(unsigned u) {
  return __uint_as_float(u << 16);
}
__device__ __forceinline__ float bf_hi(unsigned u) {
  return __uint_as_float(u & 0xFFFF0000u);
}

// Fused: feat->bf16 conversion slice + edge binning into per-(region,block)
// cells via LDS int cursors. EXACT copy of the R8/R14/R16 kernel.
__global__ __launch_bounds__(1024) void prep_kernel(
    const float4* __restrict__ feat4, const int* __restrict__ src,
    const int* __restrict__ dst, ushort* __restrict__ hb,
    int* __restrict__ cnt2, unsigned* __restrict__ rbuf) {
  __shared__ int cur[NREG];
  int tid = threadIdx.x, blk = blockIdx.x;
  if (tid < NREG) cur[tid] = 0;

  int e0 = blk * EPB + tid * 4;
  bool valid = (e0 + 4 <= N_EDGES);  // N_EDGES % 4 == 0
  int4 d4 = {0, 0, 0, 0}, s4 = {0, 0, 0, 0};
  if (valid) {
    d4 = *reinterpret_cast<const int4*>(dst + e0);
    s4 = *reinterpret_cast<const int4*>(src + e0);
  }

  // bf16 conversion: 4096 float4 per block (196*4096 >= 800000 float4s).
  int cb = blk * 4096 + tid;
#pragma unroll
  for (int k = 0; k < 4; ++k) {
    int t = cb + k * 1024;
    if (t < N_NODES * D / 4) {
      float4 f = feat4[t];
      ushort4 h;
      h.x = to_bf16(f.x); h.y = to_bf16(f.y);
      h.z = to_bf16(f.z); h.w = to_bf16(f.w);
      *reinterpret_cast<ushort4*>(hb + t * 4) = h;
    }
  }
  __syncthreads();

  if (valid) {
    const int dd[4] = {d4.x, d4.y, d4.z, d4.w};
    const int ss[4] = {s4.x, s4.y, s4.z, s4.w};
#pragma unroll
    for (int k = 0; k < 4; ++k) {
      int r = dd[k] / RSZ;  // magic-mul
      unsigned pk = ((unsigned)(dd[k] - r * RSZ) << 16) | (unsigned)ss[k];
      int p = atomicAdd(&cur[r], 1);
      if (p < CELLCAP)
        rbuf[(size_t)(r * NBINB + blk) * CELLCAP + p] = pk;
    }
  }
  __syncthreads();
  if (tid < NREG) {
    int c = cur[tid];
    cnt2[tid * NBINB + blk] = (c > CELLCAP) ? CELLCAP : c;
  }
}

// One block per region. Wave-scan sort prologue (R14/R16); 8-lane-group bf16
// gather; nodes are handed out DYNAMICALLY via an LDS work queue so finished
// groups steal remaining nodes (static n/g+128 split left the critical wave
// with ~2x the balanced load). One node live per group (no multi-node
// register blocking — spills at the 128-VGPR cap, R12/R15).
__global__ __launch_bounds__(1024) void gin_kernel(
    const float* __restrict__ feat, const ushort* __restrict__ hb,
    const float* __restrict__ W, const float* __restrict__ b,
    const float* __restrict__ eps, const int* __restrict__ cnt2,
    const unsigned* __restrict__ rbuf, float* __restrict__ out) {
  __shared__ float Wt[D * D];       // 16 KB: Wt[i*64+o] = W[o*64+i]
  __shared__ unsigned ebuf[RECAP];  // 18 KB
  __shared__ ushort sorted[RECAP];  // 9 KB
  __shared__ int cellstart[NBINB + 1];
  __shared__ int hist[RSZ], nstart[RSZ + 1], cursor[RSZ];
  __shared__ int wsum[4], wsum2[4];
  __shared__ int wq;  // dynamic node queue head

  int tid = threadIdx.x, r = blockIdx.x;
  int lane = tid & 63, wv = tid >> 6;
  for (int q = tid; q < D * D; q += 1024) Wt[q] = W[((q & 63) << 6) + (q >> 6)];
  if (tid < RSZ) hist[tid] = 0;
  if (tid == 0) wq = 0;

  // ---- scan 1: 196 cell counts, wave-level (no barriers inside) ----
  int c = (tid < NBINB) ? cnt2[r * NBINB + tid] : 0;
  int inc = c;
#pragma unroll
  for (int dlt = 1; dlt < 64; dlt <<= 1) {
    int t = __shfl_up(inc, (unsigned)dlt, 64);
    if (lane >= dlt) inc += t;
  }
  if (tid < 256 && lane == 63) wsum[wv] = inc;
  __syncthreads();  // B1
  if (tid < 256) {
    int prefix = inc - c;
    if (wv > 0) prefix += wsum[0];
    if (wv > 1) prefix += wsum[1];
    if (wv > 2) prefix += wsum[2];
    if (tid < NBINB) cellstart[tid] = prefix;
  }
  if (tid == 0) cellstart[NBINB] = wsum[0] + wsum[1] + wsum[2] + wsum[3];
  __syncthreads();  // B2
  int T = cellstart[NBINB];
  if (T > RECAP) T = RECAP;  // statistically impossible

  {  // Concatenate cells into ebuf: 4 threads per cell, uint4 loads.
    int cell = tid >> 2, sub = tid & 3;
    if (cell < NBINB) {
      int cs = cellstart[cell];
      int cc = cellstart[cell + 1] - cs;
      const unsigned* cp = rbuf + (size_t)(r * NBINB + cell) * CELLCAP;
      for (int i = sub * 4; i < cc; i += 16) {
        uint4 v = *reinterpret_cast<const uint4*>(cp + i);
        if (cs + i + 0 < T && i + 0 < cc) ebuf[cs + i + 0] = v.x;
        if (cs + i + 1 < T && i + 1 < cc) ebuf[cs + i + 1] = v.y;
        if (cs + i + 2 < T && i + 2 < cc) ebuf[cs + i + 2] = v.z;
        if (cs + i + 3 < T && i + 3 < cc) ebuf[cs + i + 3] = v.w;
      }
    }
  }
  __syncthreads();  // B3

  // Histogram by local node (int LDS atomics — cheap).
  for (int e = tid; e < T; e += 1024) atomicAdd(&hist[ebuf[e] >> 16], 1);
  __syncthreads();  // B4

  // ---- scan 2: 196 node counts, wave-level ----
  int h = (tid < RSZ) ? hist[tid] : 0;
  int inc2 = h;
#pragma unroll
  for (int dlt = 1; dlt < 64; dlt <<= 1) {
    int t = __shfl_up(inc2, (unsigned)dlt, 64);
    if (lane >= dlt) inc2 += t;
  }
  if (tid < 256 && lane == 63) wsum2[wv] = inc2;
  __syncthreads();  // B5
  if (tid < 256) {
    int prefix = inc2 - h;
    if (wv > 0) prefix += wsum2[0];
    if (wv > 1) prefix += wsum2[1];
    if (wv > 2) prefix += wsum2[2];
    if (tid < RSZ) {
      nstart[tid] = prefix;
      cursor[tid] = prefix;
    }
  }
  if (tid == 0) nstart[RSZ] = wsum2[0] + wsum2[1] + wsum2[2] + wsum2[3];
  __syncthreads();  // B6
  for (int e = tid; e < T; e += 1024) {
    unsigned pk = ebuf[e];
    int p = atomicAdd(&cursor[pk >> 16], 1);
    sorted[p] = (ushort)(pk & 0xFFFFu);
  }
  __syncthreads();  // B7

  // 128 groups x 8 lanes; lane owns feature slots j8..j8+7 (one uint4 of hb).
  // Nodes pulled from the LDS work queue (work-conserving load balance).
  int j8 = (tid & 7) << 3;
  float s = 1.0f + eps[0];

  for (;;) {
    int n = 0;
    if ((tid & 7) == 0) n = atomicAdd(&wq, 1);
    n = __shfl(n, 0, 8);  // broadcast within the 8-lane group
    if (n >= RSZ) break;

    int node = r * RSZ + n;
    if (node >= N_NODES) continue;  // region 255 tail: no loads, re-grab

    float acc[8];
    {  // self term in fp32 (exact residual path)
      const float4 fa = *reinterpret_cast<const float4*>(feat + (node << 6) + j8);
      const float4 fb = *reinterpret_cast<const float4*>(feat + (node << 6) + j8 + 4);
      acc[0] = s * fa.x; acc[1] = s * fa.y; acc[2] = s * fa.z; acc[3] = s * fa.w;
      acc[4] = s * fb.x; acc[5] = s * fb.y; acc[6] = s * fb.z; acc[7] = s * fb.w;
    }

    int e = nstart[n], e1 = nstart[n + 1];
    for (; e + 8 <= e1; e += 8) {
      int i0 = sorted[e + 0], i1 = sorted[e + 1], i2 = sorted[e + 2], i3 = sorted[e + 3];
      int i4_ = sorted[e + 4], i5 = sorted[e + 5], i6 = sorted[e + 6], i7 = sorted[e + 7];
      const uint4 h0 = *reinterpret_cast<const uint4*>(hb + (i0 << 6) + j8);
      const uint4 h1 = *reinterpret_cast<const uint4*>(hb + (i1 << 6) + j8);
      const uint4 h2 = *reinterpret_cast<const uint4*>(hb + (i2 << 6) + j8);
      const uint4 h3 = *reinterpret_cast<const uint4*>(hb + (i3 << 6) + j8);
      const uint4 h4 = *reinterpret_cast<const uint4*>(hb + (i4_ << 6) + j8);
      const uint4 h5 = *reinterpret_cast<const uint4*>(hb + (i5 << 6) + j8);
      const uint4 h6 = *reinterpret_cast<const uint4*>(hb + (i6 << 6) + j8);
      const uint4 h7 = *reinterpret_cast<const uint4*>(hb + (i7 << 6) + j8);
      acc[0] += (bf_lo(h0.x) + bf_lo(h1.x)) + (bf_lo(h2.x) + bf_lo(h3.x))
              + (bf_lo(h4.x) + bf_lo(h5.x)) + (bf_lo(h6.x) + bf_lo(h7.x));
      acc[1] += (bf_hi(h0.x) + bf_hi(h1.x)) + (bf_hi(h2.x) + bf_hi(h3.x))
              + (bf_hi(h4.x) + bf_hi(h5.x)) + (bf_hi(h6.x) + bf_hi(h7.x));
      acc[2] += (bf_lo(h0.y) + bf_lo(h1.y)) + (bf_lo(h2.y) + bf_lo(h3.y))
              + (bf_lo(h4.y) + bf_lo(h5.y)) + (bf_lo(h6.y) + bf_lo(h7.y));
      acc[3] += (bf_hi(h0.y) + bf_hi(h1.y)) + (bf_hi(h2.y) + bf_hi(h3.y))
              + (bf_hi(h4.y) + bf_hi(h5.y)) + (bf_hi(h6.y) + bf_hi(h7.y));
      acc[4] += (bf_lo(h0.z) + bf_lo(h1.z)) + (bf_lo(h2.z) + bf_lo(h3.z))
              + (bf_lo(h4.z) + bf_lo(h5.z)) + (bf_lo(h6.z) + bf_lo(h7.z));
      acc[5] += (bf_hi(h0.z) + bf_hi(h1.z)) + (bf_hi(h2.z) + bf_hi(h3.z))
              + (bf_hi(h4.z) + bf_hi(h5.z)) + (bf_hi(h6.z) + bf_hi(h7.z));
      acc[6] += (bf_lo(h0.w) + bf_lo(h1.w)) + (bf_lo(h2.w) + bf_lo(h3.w))
              + (bf_lo(h4.w) + bf_lo(h5.w)) + (bf_lo(h6.w) + bf_lo(h7.w));
      acc[7] += (bf_hi(h0.w) + bf_hi(h1.w)) + (bf_hi(h2.w) + bf_hi(h3.w))
              + (bf_hi(h4.w) + bf_hi(h5.w)) + (bf_hi(h6.w) + bf_hi(h7.w));
    }
    for (; e < e1; ++e) {
      int sn = sorted[e];
      const uint4 hv = *reinterpret_cast<const uint4*>(hb + (sn << 6) + j8);
      acc[0] += bf_lo(hv.x); acc[1] += bf_hi(hv.x);
      acc[2] += bf_lo(hv.y); acc[3] += bf_hi(hv.y);
      acc[4] += bf_lo(hv.z); acc[5] += bf_hi(hv.z);
      acc[6] += bf_lo(hv.w); acc[7] += bf_hi(hv.w);
    }

    // Matvec: feature i lives in lane (i>>3), slot (i&7) — both constant
    // under full unroll, so acc stays in registers (SROA-safe).
    float res[8];
    {
      const float4 ba = *reinterpret_cast<const float4*>(b + j8);
      const float4 bb = *reinterpret_cast<const float4*>(b + j8 + 4);
      res[0] = ba.x; res[1] = ba.y; res[2] = ba.z; res[3] = ba.w;
      res[4] = bb.x; res[5] = bb.y; res[6] = bb.z; res[7] = bb.w;
    }
#pragma unroll
    for (int i = 0; i < D; ++i) {
      float rv = __shfl(acc[i & 7], i >> 3, 8);  // rst[node][i]
      const float4 wa = *reinterpret_cast<const float4*>(Wt + i * D + j8);
      const float4 wb = *reinterpret_cast<const float4*>(Wt + i * D + j8 + 4);
      res[0] += rv * wa.x; res[1] += rv * wa.y;
      res[2] += rv * wa.z; res[3] += rv * wa.w;
      res[4] += rv * wb.x; res[5] += rv * wb.y;
      res[6] += rv * wb.z; res[7] += rv * wb.w;
    }
    float4 o0, o1;
    o0.x = res[0]; o0.y = res[1]; o0.z = res[2]; o0.w = res[3];
    o1.x = res[4]; o1.y = res[5]; o1.z = res[6]; o1.w = res[7];
    *reinterpret_cast<float4*>(out + (node << 6) + j8) = o0;
    *reinterpret_cast<float4*>(out + (node << 6) + j8 + 4) = o1;
  }
}

extern "C" void kernel_launch(void* const* d_in, const int* in_sizes, int n_in,
                              void* d_out, int out_size, void* d_ws, size_t ws_size,
                              hipStream_t stream) {
  const float* feat = (const float*)d_in[0];
  const float* W    = (const float*)d_in[1];
  const float* b    = (const float*)d_in[2];
  const float* eps  = (const float*)d_in[3];
  const int*   src  = (const int*)d_in[4];
  const int*   dst  = (const int*)d_in[5];
  float* out = (float*)d_out;

  int* ws = (int*)d_ws;
  int* cnt2      = ws + WS_CNT2;
  unsigned* rbuf = (unsigned*)(ws + WS_RBUF);
  ushort* hb     = (ushort*)((char*)d_ws + WS_HB_BYTE);

  hipLaunchKernelGGL(prep_kernel, dim3(NBINB), dim3(1024), 0, stream,
                     (const float4*)feat, src, dst, hb, cnt2, rbuf);
  hipLaunchKernelGGL(gin_kernel, dim3(NREG), dim3(1024), 0, stream,
                     feat, hb, W, b, eps, cnt2, rbuf, out);
}